// Round 5
// baseline (6399.765 us; speedup 1.0000x reference)
//
#include <hip/hip_runtime.h>
#include <stdint.h>

#define DI __device__ __forceinline__

typedef _Float16 f16x8 __attribute__((ext_vector_type(8)));
typedef float f32x4 __attribute__((ext_vector_type(4)));
typedef unsigned long long u64;
typedef unsigned short u16;

// ---- problem constants ----
constexpr int kB = 4;
constexpr int kN = 65536;
constexpr int kG = 512;   // NUM_GROUP
constexpr int kM = 64;    // GROUP_SIZE
constexpr int kE = 60;    // EMB
constexpr int GRD = 20;   // KNN grid resolution
constexpr int NCELL = GRD * GRD * GRD;
constexpr float CW = 1.0f / 20.0f;

constexpr int NCH = 2048;   // FPS chunks per batch (32 sorted points each)
constexpr int CHSZ = 32;
constexpr int NWORK = 504;  // worker blocks
constexpr int NBLK = 512;   // 4 fps + 504 workers + 4 dummies

// ---- workspace layout (bytes) ----
// cline per (b,it): 128B line, 3 tagged words: (coord_bits<<32)|(it+1). 1 writer.
constexpr size_t OFF_CLINE  = 0;
constexpr size_t OFF_CCNT   = OFF_CLINE + (size_t)kB * kG * 128;   // 256KB
constexpr size_t OFF_GS     = OFF_CCNT + (size_t)kB * NCELL * 4;   // phase counters
constexpr size_t ZERO_BYTES = OFF_GS + 64;
constexpr size_t OFF_CSTART = (ZERO_BYTES + 255) & ~(size_t)255;   // kB*(NCELL+1) u32
constexpr size_t OFF_CUR    = OFF_CSTART + (size_t)kB * (NCELL + 1) * 4;
constexpr size_t OFF_DD     = ((OFF_CUR + (size_t)kB * NCELL * 4) + 255) & ~(size_t)255;
constexpr size_t OFF_SW1    = (OFF_DD + (size_t)kB * kN * 4 + 255) & ~(size_t)255;
constexpr size_t OFF_SW2    = OFF_SW1 + 2048 * 2;
constexpr size_t OFF_SW3    = OFF_SW2 + 8192 * 2;
constexpr size_t OFF_SW4    = OFF_SW3 + 32768 * 2;
constexpr size_t OFF_WPT    = OFF_SW4 + 131072 * 2;
constexpr size_t OFF_SORT   = ((OFF_WPT + 60 * 512 * 4) + 255) & ~(size_t)255; // kB*kN float4

DI int cellof(float x) {
  int c = (int)(x * (float)GRD);
  return min(GRD - 1, max(0, c));
}
DI unsigned orderable(float f) {
  unsigned u = __float_as_uint(f);
  return (u & 0x80000000u) ? ~u : (u | 0x80000000u);
}
DI _Float16 f16dn(float v) {   // round toward -inf (v in [0,1))
  _Float16 h = (_Float16)v;
  if ((float)h > v) h = __builtin_bit_cast(_Float16, (u16)(__builtin_bit_cast(u16, h) - 1));
  return h;
}
DI _Float16 f16up(float v) {   // round toward +inf (v in [0,1))
  _Float16 h = (_Float16)v;
  if ((float)h < v) h = __builtin_bit_cast(_Float16, (u16)(__builtin_bit_cast(u16, h) + 1));
  return h;
}

// =====================  zero the sync/count region  =====================
__global__ void k_zero(uint32_t* p, int nwords) {
  int i = blockIdx.x * blockDim.x + threadIdx.x;
  int st = gridDim.x * blockDim.x;
  for (; i < nwords; i += st) p[i] = 0u;
}

// =====================  weight prep: B-fragment swizzle (f16) + WpT  =====================
DI void swz(const float* __restrict__ W, _Float16* __restrict__ sw,
            int total, int nks, int Kreal, int N, int i0, int st) {
  for (int i = i0; i < total; i += st) {
    int j = i & 7, lane = (i >> 3) & 63, rest = i >> 9;
    int ks = rest % nks, nt = rest / nks;
    int k = ks * 32 + ((lane >> 4) << 3) + j;
    int n = nt * 16 + (lane & 15);
    sw[i] = (_Float16)((k < Kreal) ? W[k * N + n] : 0.f);
  }
}

__global__ void k_prep(const float* __restrict__ W1, const float* __restrict__ W2,
                       const float* __restrict__ W3, const float* __restrict__ W4,
                       const float* __restrict__ Wp,
                       _Float16* __restrict__ sw1, _Float16* __restrict__ sw2,
                       _Float16* __restrict__ sw3, _Float16* __restrict__ sw4,
                       float* __restrict__ wpt) {
  int i0 = blockIdx.x * blockDim.x + threadIdx.x;
  int st = gridDim.x * blockDim.x;
  swz(W1, sw1, 2048, 1, 6, 64, i0, st);
  swz(W2, sw2, 8192, 2, 64, 128, i0, st);
  swz(W3, sw3, 32768, 4, 128, 256, i0, st);
  swz(W4, sw4, 131072, 8, 256, 512, i0, st);
  for (int i = i0; i < 60 * 512; i += st) { int n = i >> 9, k = i & 511; wpt[i] = Wp[k * 60 + n]; }
}

// =====================  device-wide phase barrier (co-resident workers)  =====================
DI void gbar(uint32_t* ctr, unsigned target) {
  __syncthreads();
  if (threadIdx.x == 0) {
    __hip_atomic_fetch_add(ctr, 1u, __ATOMIC_ACQ_REL, __HIP_MEMORY_SCOPE_AGENT);
    long bail = 0;
    while (__hip_atomic_load(ctr, __ATOMIC_ACQUIRE, __HIP_MEMORY_SCOPE_AGENT) < target) {
      __builtin_amdgcn_s_sleep(32);
      if (++bail > 100000000L) break;
    }
  }
  __syncthreads();
}

// =====================  FPS: one block per batch, bound-skip chunks  ===========
// Serial chain is intra-CU: bound test (LDS/regs) -> refine queued chunks (L2) ->
// LDS argmax -> fire-and-forget publish. No cross-block wait per round.
// LDS layout (fps path):
//   [0,16384)       ckey u64[2048]        exact per-chunk (maxdd | ~origidx)
//   [16384,40960)   cxyz float[2048][3]   coords of chunk's best point
//   [40960,65536)   cbb  f16[2048][6]     outward-rounded chunk bbox
//   [65536,69632)   queue u16[2048]
//   [69632,69760)   misc: qn, wkey[4], wcid[4], wslot
DI void fps_block(const float* __restrict__ xyz, float* __restrict__ outC,
                  u64* __restrict__ cline, uint32_t* __restrict__ gs,
                  const float4* __restrict__ sorted_g, float* __restrict__ dd_g,
                  int b, char* smem) {
  __builtin_amdgcn_s_setprio(3);
  const int tid = threadIdx.x;
  const int wave = tid >> 6, lane = tid & 63;
  const int h = tid >> 5, sub = tid & 31;     // half-wave id 0..7, lane-in-half
  const float* X = xyz + (size_t)b * kN * 3;
  const float4* SP = sorted_g + (size_t)b * kN;
  float* DD = dd_g + (size_t)b * kN;
  u64* cl = cline + (size_t)b * kG * 16;

  u64* ckey = (u64*)smem;
  float* cxyz = (float*)(smem + 16384);
  _Float16* cbb = (_Float16*)(smem + 40960);
  u16* queue = (u16*)(smem + 65536);
  int* qn = (int*)(smem + 69632);
  u64* wkey = (u64*)(smem + 69640);
  int* wcid = (int*)(smem + 69672);
  float4* wslot = (float4*)(smem + 69696);

  float cx = X[0], cy = X[1], cz = X[2];
  if (tid == 0) {
    // publish center 0 immediately (independent of grid build)
    u64 tg = 1u;
    __hip_atomic_store(cl + 0, ((u64)__float_as_uint(cx) << 32) | tg, __ATOMIC_RELAXED, __HIP_MEMORY_SCOPE_AGENT);
    __hip_atomic_store(cl + 1, ((u64)__float_as_uint(cy) << 32) | tg, __ATOMIC_RELAXED, __HIP_MEMORY_SCOPE_AGENT);
    __hip_atomic_store(cl + 2, ((u64)__float_as_uint(cz) << 32) | tg, __ATOMIC_RELAXED, __HIP_MEMORY_SCOPE_AGENT);
    outC[(size_t)b * kG * 3 + 0] = cx;
    outC[(size_t)b * kG * 3 + 1] = cy;
    outC[(size_t)b * kG * 3 + 2] = cz;
    // wait for workers' grid build (acquire -> invalidates caches for SP reads)
    long bail = 0;
    while (__hip_atomic_load(gs + 2, __ATOMIC_ACQUIRE, __HIP_MEMORY_SCOPE_AGENT) < NWORK) {
      __builtin_amdgcn_s_sleep(16);
      if (++bail > 200000000L) break;
    }
    *qn = 0;
  }
  __syncthreads();

  // bbox per chunk (outward-rounded f16), half-wave cooperative; streams SP once
  for (int c = h; c < NCH; c += 8) {
    float4 p = SP[c * CHSZ + sub];
    float mnx = p.x, mxx = p.x, mny = p.y, mxy = p.y, mnz = p.z, mxz = p.z;
#pragma unroll
    for (int off = 16; off; off >>= 1) {
      mnx = fminf(mnx, __shfl_down(mnx, (unsigned)off));
      mxx = fmaxf(mxx, __shfl_down(mxx, (unsigned)off));
      mny = fminf(mny, __shfl_down(mny, (unsigned)off));
      mxy = fmaxf(mxy, __shfl_down(mxy, (unsigned)off));
      mnz = fminf(mnz, __shfl_down(mnz, (unsigned)off));
      mxz = fmaxf(mxz, __shfl_down(mxz, (unsigned)off));
    }
    if (sub == 0) {
      cbb[c * 6 + 0] = f16dn(mnx); cbb[c * 6 + 1] = f16up(mxx);
      cbb[c * 6 + 2] = f16dn(mny); cbb[c * 6 + 3] = f16up(mxy);
      cbb[c * 6 + 4] = f16dn(mnz); cbb[c * 6 + 5] = f16up(mxz);
    }
  }
  __syncthreads();

  for (int it = 1; it < kG; ++it) {
    // ---- Phase A: bound tests -> ballot-compressed queue (skip for it==1) ----
    if (it > 1) {
#pragma unroll
      for (int i = 0; i < 8; ++i) {
        int c = (i << 8) + tid;
        int c6 = c * 6;
        float lox = (float)cbb[c6 + 0], hix = (float)cbb[c6 + 1];
        float loy = (float)cbb[c6 + 2], hiy = (float)cbb[c6 + 3];
        float loz = (float)cbb[c6 + 4], hiz = (float)cbb[c6 + 5];
        float dx = fmaxf(fmaxf(lox - cx, cx - hix), 0.f);
        float dy = fmaxf(fmaxf(loy - cy, cy - hiy), 0.f);
        float dz = fmaxf(fmaxf(loz - cz, cz - hiz), 0.f);
        float lb = dx * dx + dy * dy + dz * dz;
        float ub = __uint_as_float((unsigned)(ckey[c] >> 32));
        bool need = !(lb * 0.999f > ub);   // conservative: skip only when provably unchanged
        u64 m = __ballot(need);
        int base = 0;
        if (lane == 0) base = atomicAdd(qn, (int)__popcll(m));
        base = __shfl(base, 0);
        int off = (int)__popcll(m & ((1ull << lane) - 1ull));
        if (need) queue[base + off] = (u16)c;
      }
    }
    __syncthreads();
    // ---- Phase B: refine queued chunks (half-wave per chunk, exact math) ----
    {
      const bool first = (it == 1);
      const int Q = first ? NCH : *qn;
      for (int t = h; t < Q; t += 8) {
        int c = first ? t : (int)queue[t];
        int g = c * CHSZ + sub;
        float4 p = SP[g];
        float ddo = first ? 1e10f : DD[g];
        float dx = __fsub_rn(p.x, cx);
        float dy = __fsub_rn(p.y, cy);
        float dz = __fsub_rn(p.z, cz);
        float d = __fadd_rn(__fadd_rn(__fmul_rn(dx, dx), __fmul_rn(dy, dy)), __fmul_rn(dz, dz));
        float nd = fminf(ddo, d);
        DD[g] = nd;
        u64 key = ((u64)__float_as_uint(nd) << 32) |
                  (u64)(0xFFFFFFFFu - (unsigned)__float_as_uint(p.w));
        float bx = p.x, by = p.y, bz = p.z;
#pragma unroll
        for (int off = 16; off; off >>= 1) {
          u64 ok = __shfl_down(key, (unsigned)off);
          float ox = __shfl_down(bx, (unsigned)off);
          float oy = __shfl_down(by, (unsigned)off);
          float oz = __shfl_down(bz, (unsigned)off);
          if (ok > key) { key = ok; bx = ox; by = oy; bz = oz; }
        }
        if (sub == 0) {
          ckey[c] = key;
          cxyz[c * 3 + 0] = bx; cxyz[c * 3 + 1] = by; cxyz[c * 3 + 2] = bz;
        }
      }
    }
    __syncthreads();
    // ---- Phase C: argmax over 2048 exact chunk keys ----
    {
      u64 key = 0ull; int cid = 0;
#pragma unroll
      for (int i = 0; i < 8; ++i) {
        int c = (i << 8) + tid;
        u64 k = ckey[c];
        if (k > key) { key = k; cid = c; }
      }
#pragma unroll
      for (int off = 32; off; off >>= 1) {
        u64 ok = __shfl_down(key, (unsigned)off);
        int oc = __shfl_down(cid, (unsigned)off);
        if (ok > key) { key = ok; cid = oc; }
      }
      if (lane == 0) { wkey[wave] = key; wcid[wave] = cid; }
    }
    __syncthreads();
    // ---- Phase D: final reduce + fire-and-forget publish ----
    if (tid == 0) {
      u64 key = wkey[0]; int cid = wcid[0];
#pragma unroll
      for (int i = 1; i < 4; ++i)
        if (wkey[i] > key) { key = wkey[i]; cid = wcid[i]; }
      float wx = cxyz[cid * 3 + 0], wy = cxyz[cid * 3 + 1], wz = cxyz[cid * 3 + 2];
      *wslot = make_float4(wx, wy, wz, 0.f);
      u64 tg = (unsigned)(it + 1);
      u64* e = cl + (size_t)it * 16;
      __hip_atomic_store(e + 0, ((u64)__float_as_uint(wx) << 32) | tg, __ATOMIC_RELAXED, __HIP_MEMORY_SCOPE_AGENT);
      __hip_atomic_store(e + 1, ((u64)__float_as_uint(wy) << 32) | tg, __ATOMIC_RELAXED, __HIP_MEMORY_SCOPE_AGENT);
      __hip_atomic_store(e + 2, ((u64)__float_as_uint(wz) << 32) | tg, __ATOMIC_RELAXED, __HIP_MEMORY_SCOPE_AGENT);
      outC[((size_t)b * kG + it) * 3 + 0] = wx;
      outC[((size_t)b * kG + it) * 3 + 1] = wy;
      outC[((size_t)b * kG + it) * 3 + 2] = wz;
      *qn = 0;
    }
    __syncthreads();
    float4 wc = *wslot;
    cx = wc.x; cy = wc.y; cz = wc.z;
  }
}

// =====================  bitonic sort (shared, 256 threads)  =====================
DI void bitonic(u64* a, int n, int tid) {
  for (int k = 2; k <= n; k <<= 1)
    for (int j = k >> 1; j > 0; j >>= 1) {
      __syncthreads();
      for (int i = tid; i < n; i += 256) {
        int ix = i ^ j;
        if (ix > i) {
          u64 x = a[i], y = a[ix];
          bool up = ((i & k) == 0);
          if ((x > y) == up) { a[i] = y; a[ix] = x; }
        }
      }
    }
  __syncthreads();
}

// =====================  MLP layers (f16 MFMA)  =====================
template <int Kdim, int Ndim, int SIN, int SOUT>
DI void mfma_layer(const _Float16* __restrict__ Xin, _Float16* __restrict__ Xout,
                   const _Float16* __restrict__ Wsw, const float* __restrict__ bias,
                   int wave, int lane) {
  constexpr int NKS = Kdim / 32;
  constexpr int NTW = Ndim / 64;
  constexpr int CH = (NTW < 4) ? NTW : 4;
  const int quad = lane >> 4, l16 = lane & 15;
  for (int c0 = 0; c0 < NTW; c0 += CH) {
    f32x4 acc[CH][4];
#pragma unroll
    for (int nt = 0; nt < CH; ++nt) {
      float bv = bias[wave * (Ndim / 4) + (c0 + nt) * 16 + l16];
#pragma unroll
      for (int m = 0; m < 4; ++m) acc[nt][m] = {bv, bv, bv, bv};
    }
#pragma unroll
    for (int ks = 0; ks < NKS; ++ks) {
      f16x8 af[4];
#pragma unroll
      for (int m = 0; m < 4; ++m)
        af[m] = *(const f16x8*)(Xin + (m * 16 + l16) * SIN + ks * 32 + quad * 8);
#pragma unroll
      for (int nt = 0; nt < CH; ++nt) {
        int ntg = wave * NTW + c0 + nt;
        f16x8 bf = *(const f16x8*)(Wsw + ((size_t)(ntg * NKS + ks) * 64 + lane) * 8);
#pragma unroll
        for (int m = 0; m < 4; ++m)
          acc[nt][m] = __builtin_amdgcn_mfma_f32_16x16x32_f16(af[m], bf, acc[nt][m], 0, 0, 0);
      }
    }
#pragma unroll
    for (int nt = 0; nt < CH; ++nt) {
      int col = wave * (Ndim / 4) + (c0 + nt) * 16 + l16;
#pragma unroll
      for (int m = 0; m < 4; ++m)
#pragma unroll
        for (int r = 0; r < 4; ++r) {
          int row = m * 16 + quad * 4 + r;
          Xout[row * SOUT + col] = (_Float16)fmaxf(acc[nt][m][r], 0.f);
        }
    }
  }
}

DI void mfma_layer4(const _Float16* __restrict__ Xin, const _Float16* __restrict__ Wsw,
                    const float* __restrict__ bias, float* __restrict__ maxv,
                    int wave, int lane) {
  constexpr int SIN = 264, NKS = 8, NTW = 8, CH = 4;
  const int quad = lane >> 4, l16 = lane & 15;
  for (int c0 = 0; c0 < NTW; c0 += CH) {
    f32x4 acc[CH][4];
#pragma unroll
    for (int nt = 0; nt < CH; ++nt) {
      float bv = bias[wave * 128 + (c0 + nt) * 16 + l16];
#pragma unroll
      for (int m = 0; m < 4; ++m) acc[nt][m] = {bv, bv, bv, bv};
    }
#pragma unroll
    for (int ks = 0; ks < NKS; ++ks) {
      f16x8 af[4];
#pragma unroll
      for (int m = 0; m < 4; ++m)
        af[m] = *(const f16x8*)(Xin + (m * 16 + l16) * SIN + ks * 32 + quad * 8);
#pragma unroll
      for (int nt = 0; nt < CH; ++nt) {
        int ntg = wave * NTW + c0 + nt;
        f16x8 bf = *(const f16x8*)(Wsw + ((size_t)(ntg * NKS + ks) * 64 + lane) * 8);
#pragma unroll
        for (int m = 0; m < 4; ++m)
          acc[nt][m] = __builtin_amdgcn_mfma_f32_16x16x32_f16(af[m], bf, acc[nt][m], 0, 0, 0);
      }
    }
#pragma unroll
    for (int nt = 0; nt < CH; ++nt) {
      float mx = 0.f;  // relu folded into max
#pragma unroll
      for (int m = 0; m < 4; ++m)
#pragma unroll
        for (int r = 0; r < 4; ++r) mx = fmaxf(mx, acc[nt][m][r]);
      mx = fmaxf(mx, __shfl_xor(mx, 16, 64));
      mx = fmaxf(mx, __shfl_xor(mx, 32, 64));
      if (quad == 0) maxv[wave * 128 + (c0 + nt) * 16 + l16] = mx;
    }
  }
}

// =====================  fused kernel  =====================
__global__ __launch_bounds__(256, 2) void k_fused(
    const float* __restrict__ xyz, const float* __restrict__ color,
    float* __restrict__ outC, float* __restrict__ outE,
    u64* __restrict__ cline, uint32_t* __restrict__ ccnt,
    uint32_t* __restrict__ cstart, uint32_t* __restrict__ cur,
    float4* __restrict__ sorted, float* __restrict__ dd_g,
    uint32_t* __restrict__ gs,
    const _Float16* __restrict__ sw1, const _Float16* __restrict__ sw2,
    const _Float16* __restrict__ sw3, const _Float16* __restrict__ sw4,
    const float* __restrict__ wpt,
    const float* __restrict__ b1, const float* __restrict__ b2,
    const float* __restrict__ b3, const float* __restrict__ b4,
    const float* __restrict__ bp) {
  __shared__ __align__(16) char smem[69760];
  const int bi = blockIdx.x;
  if (bi < kB) {  // FPS block for batch bi (CU slot 0 on XCD bi)
    fps_block(xyz, outC, cline, gs, sorted, dd_g, bi, smem);
    return;
  }
  if (bi >= 256 && bi < 256 + kB) return;  // dummy: frees second slot of FPS CUs

  // ---------------- worker block ----------------
  const int wj = (bi < 256) ? (bi - kB) : (bi - 256 - kB + (256 - kB));  // 0..503
  const int tid = threadIdx.x;
  const int wave = tid >> 6, lane = tid & 63;
  __shared__ int nC;
  __shared__ float4 spc;
  __shared__ uint32_t s_part[256];
  u64* cand = (u64*)smem;

  // ---- grid build ----
  for (int i = wj * 256 + tid; i < kB * kN; i += NWORK * 256) {
    int b = i >> 16, p = i & (kN - 1);
    const float* q = xyz + ((size_t)b * kN + p) * 3;
    int cid = (cellof(q[2]) * GRD + cellof(q[1])) * GRD + cellof(q[0]);
    atomicAdd(&ccnt[b * NCELL + cid], 1u);
  }
  gbar(gs + 0, NWORK);
  if (wj < kB) {
    int b = wj;
    const uint32_t* cc = ccnt + (size_t)b * NCELL;
    uint32_t* cs = cstart + (size_t)b * (NCELL + 1);
    uint32_t* cu = cur + (size_t)b * NCELL;
    const int chunk = 32;
    int c0 = tid * chunk;
    uint32_t s = 0;
    for (int i = 0; i < chunk; ++i) { int c = c0 + i; if (c < NCELL) s += cc[c]; }
    s_part[tid] = s;
    __syncthreads();
    for (int off = 1; off < 256; off <<= 1) {
      uint32_t add = (tid >= off) ? s_part[tid - off] : 0u;
      __syncthreads();
      s_part[tid] += add;
      __syncthreads();
    }
    uint32_t run = s_part[tid] - s;
    for (int i = 0; i < chunk; ++i) {
      int c = c0 + i;
      if (c < NCELL) { cs[c] = run; cu[c] = run; run += cc[c]; }
    }
    if (tid == 255) cs[NCELL] = run;
  }
  gbar(gs + 1, NWORK);
  for (int i = wj * 256 + tid; i < kB * kN; i += NWORK * 256) {
    int b = i >> 16, p = i & (kN - 1);
    const float* q = xyz + ((size_t)b * kN + p) * 3;
    float x = q[0], y = q[1], z = q[2];
    int cid = (cellof(z) * GRD + cellof(y)) * GRD + cellof(x);
    uint32_t pos = atomicAdd(&cur[b * NCELL + cid], 1u);
    sorted[(size_t)b * kN + pos] = make_float4(x, y, z, __uint_as_float((unsigned)p));
  }
  gbar(gs + 2, NWORK);   // FPS blocks wait on this counter too

  // ---- consume groups in production order: job j = it*4 + b ----
  for (int j = wj; j < kB * kG; j += NWORK) {
    const int it = j >> 2, b = j & 3;
    if (tid < 64) {
      const u64* e = cline + ((size_t)b * kG + it) * 16;
      u64 v = 0; long bail = 0;
      for (;;) {
        if (lane < 3)
          v = __hip_atomic_load(e + lane, __ATOMIC_RELAXED, __HIP_MEMORY_SCOPE_AGENT);
        bool ok = (lane >= 3) || ((unsigned)v == (unsigned)(it + 1));
        if (__all(ok)) break;
        __builtin_amdgcn_s_sleep(8);
        if (++bail > 100000000L) break;
      }
      u64 v0 = __shfl(v, 0), v1 = __shfl(v, 1), v2 = __shfl(v, 2);
      if (tid == 0)
        spc = make_float4(__uint_as_float((unsigned)(v0 >> 32)),
                          __uint_as_float((unsigned)(v1 >> 32)),
                          __uint_as_float((unsigned)(v2 >> 32)), 0.f);
    }
    __syncthreads();
    const float cx = spc.x, cy = spc.y, cz = spc.z;

    // ---- KNN (expanding box + exact re-rank + bitonic) ----
    const float nc = __fadd_rn(__fadd_rn(__fmul_rn(cx, cx), __fmul_rn(cy, cy)), __fmul_rn(cz, cz));
    const float4* SPb = sorted + (size_t)b * kN;
    const uint32_t* CS = cstart + (size_t)b * (NCELL + 1);
    const int ccx = cellof(cx), ccy = cellof(cy), ccz = cellof(cz);
    if (tid == 0) nC = 0;
    __syncthreads();
    int plox = 1, phix = 0, ploy = 1, phiy = 0, ploz = 1, phiz = 0;
    for (int r = 1; r <= GRD; ++r) {
      int lox = max(0, ccx - r), hix = min(GRD - 1, ccx + r);
      int loy = max(0, ccy - r), hiy = min(GRD - 1, ccy + r);
      int loz = max(0, ccz - r), hiz = min(GRD - 1, ccz + r);
      for (int z = loz; z <= hiz; ++z)
        for (int y = loy; y <= hiy; ++y) {
          bool rowPrev = (r > 1) && (z >= ploz && z <= phiz && y >= ploy && y <= phiy);
          for (int s = 0; s < 2; ++s) {
            int xa, xb;
            if (!rowPrev) { if (s) break; xa = lox; xb = hix; }
            else if (s == 0) { xa = lox; xb = plox - 1; }
            else { xa = phix + 1; xb = hix; }
            if (xa > xb) continue;
            int c0 = (z * GRD + y) * GRD + xa;
            int i0 = CS[c0];
            int i1 = CS[(z * GRD + y) * GRD + xb + 1];
            for (int i = i0 + tid; i < i1; i += 256) {
              float4 pt = SPb[i];
              float npn = __fadd_rn(__fadd_rn(__fmul_rn(pt.x, pt.x), __fmul_rn(pt.y, pt.y)),
                                    __fmul_rn(pt.z, pt.z));
              float dot = __fadd_rn(__fadd_rn(__fmul_rn(cx, pt.x), __fmul_rn(cy, pt.y)),
                                    __fmul_rn(cz, pt.z));
              float sq = __fsub_rn(__fadd_rn(nc, npn), __fmul_rn(2.0f, dot));
              unsigned key = orderable(sq);
              int pos = atomicAdd(&nC, 1);
              if (pos < 8192)
                cand[pos] = ((u64)key << 32) | (unsigned)__float_as_uint(pt.w);
            }
          }
        }
      __syncthreads();
      int n = min(nC, 8192);
      float rc = 1e30f;
      if (lox > 0) rc = fminf(rc, cx - (float)lox * CW);
      if (hix < GRD - 1) rc = fminf(rc, (float)(hix + 1) * CW - cx);
      if (loy > 0) rc = fminf(rc, cy - (float)loy * CW);
      if (hiy < GRD - 1) rc = fminf(rc, (float)(hiy + 1) * CW - cy);
      if (loz > 0) rc = fminf(rc, cz - (float)loz * CW);
      if (hiz < GRD - 1) rc = fminf(rc, (float)(hiz + 1) * CW - cz);
      float r2 = (rc >= 1e29f) ? 3.0e38f : rc * rc * (1.0f - 1e-5f);
      unsigned keyR = orderable(r2);
      bool done = false;
      if (n >= kM) {
        int np2 = 1;
        while (np2 < n) np2 <<= 1;
        for (int i = n + tid; i < np2; i += 256) cand[i] = ~0ull;
        bitonic(cand, np2, tid);
        unsigned k63 = (unsigned)(cand[kM - 1] >> 32);
        done = (k63 <= keyR);
        if (tid == 0) nC = n;
      }
      __syncthreads();
      if (done) break;
      plox = lox; phix = hix; ploy = loy; phiy = hiy; ploz = loz; phiz = hiz;
    }

    // ---- MLP (reuses smem; neighbor indices straight from cand) ----
    uint32_t pidx = 0;
    if (tid < kM) pidx = (uint32_t)(cand[tid] & 0xFFFFFFFFu);
    __syncthreads();
    _Float16* bufA = (_Float16*)smem;
    _Float16* bufB = (_Float16*)(smem + 17408);
    float* maxv = (float*)smem;
    float* psum = (float*)(smem + 2048);
    if (tid < kM) {
      const float* xp = xyz + ((size_t)b * kN + pidx) * 3;
      const float* cp = color + ((size_t)b * kN + pidx) * 3;
      f16x8 v = {};
      v[0] = (_Float16)__fsub_rn(xp[0], cx);
      v[1] = (_Float16)__fsub_rn(xp[1], cy);
      v[2] = (_Float16)__fsub_rn(xp[2], cz);
      v[3] = (_Float16)cp[0];
      v[4] = (_Float16)cp[1];
      v[5] = (_Float16)cp[2];
      f16x8 zf = {};
      *(f16x8*)(bufA + tid * 40 + 0) = v;
      *(f16x8*)(bufA + tid * 40 + 8) = zf;
      *(f16x8*)(bufA + tid * 40 + 16) = zf;
      *(f16x8*)(bufA + tid * 40 + 24) = zf;
    }
    __syncthreads();
    mfma_layer<32, 64, 40, 72>(bufA, bufB, sw1, b1, wave, lane);
    __syncthreads();
    mfma_layer<64, 128, 72, 136>(bufB, bufA, sw2, b2, wave, lane);
    __syncthreads();
    mfma_layer<128, 256, 136, 264>(bufA, bufB, sw3, b3, wave, lane);
    __syncthreads();
    mfma_layer4(bufB, sw4, b4, maxv, wave, lane);
    __syncthreads();
    if (tid < 240) {
      int jj = tid >> 2, q = tid & 3;
      const float* w = wpt + (size_t)jj * 512 + q * 128;
      float s = 0.f;
#pragma unroll 4
      for (int k = 0; k < 128; ++k) s = fmaf(maxv[q * 128 + k], w[k], s);
      psum[tid] = s;
    }
    __syncthreads();
    if (tid < kE) {
      float e = __fadd_rn(__fadd_rn(psum[tid * 4 + 0], psum[tid * 4 + 1]),
                          __fadd_rn(psum[tid * 4 + 2], psum[tid * 4 + 3])) + bp[tid];
      outE[((size_t)b * kG + it) * kE + tid] = e;
    }
    __syncthreads();  // smem reuse fence before next job
  }
}

// =====================  launch  =====================
extern "C" void kernel_launch(void* const* d_in, const int* in_sizes, int n_in,
                              void* d_out, int out_size, void* d_ws, size_t ws_size,
                              hipStream_t stream) {
  (void)in_sizes; (void)n_in; (void)out_size; (void)ws_size;
  const float* xyz = (const float*)d_in[0];
  const float* color = (const float*)d_in[1];
  const float* W1 = (const float*)d_in[2];
  const float* b1 = (const float*)d_in[3];
  const float* W2 = (const float*)d_in[4];
  const float* b2 = (const float*)d_in[5];
  const float* W3 = (const float*)d_in[6];
  const float* b3 = (const float*)d_in[7];
  const float* W4 = (const float*)d_in[8];
  const float* b4 = (const float*)d_in[9];
  const float* Wp = (const float*)d_in[10];
  const float* bp = (const float*)d_in[11];

  char* ws = (char*)d_ws;
  auto cline = (u64*)(ws + OFF_CLINE);
  auto ccnt = (uint32_t*)(ws + OFF_CCNT);
  auto gs = (uint32_t*)(ws + OFF_GS);
  auto cstart = (uint32_t*)(ws + OFF_CSTART);
  auto cur = (uint32_t*)(ws + OFF_CUR);
  auto dd = (float*)(ws + OFF_DD);
  auto sw1 = (_Float16*)(ws + OFF_SW1);
  auto sw2 = (_Float16*)(ws + OFF_SW2);
  auto sw3 = (_Float16*)(ws + OFF_SW3);
  auto sw4 = (_Float16*)(ws + OFF_SW4);
  auto wpt = (float*)(ws + OFF_WPT);
  auto sorted = (float4*)(ws + OFF_SORT);

  float* outE = (float*)d_out;
  float* outC = outE + (size_t)kB * kG * kE;

  k_zero<<<256, 256, 0, stream>>>((uint32_t*)ws, (int)(ZERO_BYTES / 4));
  k_prep<<<256, 256, 0, stream>>>(W1, W2, W3, W4, Wp, sw1, sw2, sw3, sw4, wpt);
  k_fused<<<NBLK, 256, 0, stream>>>(xyz, color, outC, outE, cline, ccnt, cstart,
                                    cur, sorted, dd, gs, sw1, sw2, sw3, sw4, wpt,
                                    b1, b2, b3, b4, bp);
}

// Round 6
// 4416.342 us; speedup vs baseline: 1.4491x; 1.4491x over previous
//
#include <hip/hip_runtime.h>
#include <stdint.h>

#define DI __device__ __forceinline__

typedef _Float16 f16x8 __attribute__((ext_vector_type(8)));
typedef float f32x4 __attribute__((ext_vector_type(4)));
typedef unsigned long long u64;
typedef unsigned short u16;

// ---- problem constants ----
constexpr int kB = 4;
constexpr int kN = 65536;
constexpr int kG = 512;   // NUM_GROUP
constexpr int kM = 64;    // GROUP_SIZE
constexpr int kE = 60;    // EMB
constexpr int GRD = 16;   // unified grid resolution (FPS chunks == cells)
constexpr int NCELL = GRD * GRD * GRD;   // 4096
constexpr float CW = 1.0f / 16.0f;

constexpr int NWORK = 504;  // worker blocks
constexpr int NBLK = 512;   // 4 fps + 504 workers + 4 dummies

// ---- workspace layout (bytes) ----
// cline per (b,it): 128B line, 3 tagged words: (coord_bits<<32)|(it+1). 1 writer.
constexpr size_t OFF_CLINE  = 0;
constexpr size_t OFF_CCNT   = OFF_CLINE + (size_t)kB * kG * 128;
constexpr size_t OFF_GS     = OFF_CCNT + (size_t)kB * NCELL * 4;
constexpr size_t ZERO_BYTES = OFF_GS + 64;
constexpr size_t OFF_CSTART = (ZERO_BYTES + 255) & ~(size_t)255;   // kB*(NCELL+1) u32
constexpr size_t OFF_CUR    = OFF_CSTART + (size_t)kB * (NCELL + 1) * 4;
constexpr size_t OFF_DD     = ((OFF_CUR + (size_t)kB * NCELL * 4) + 255) & ~(size_t)255;
constexpr size_t OFF_SW1    = (OFF_DD + (size_t)kB * kN * 4 + 255) & ~(size_t)255;
constexpr size_t OFF_SW2    = OFF_SW1 + 2048 * 2;
constexpr size_t OFF_SW3    = OFF_SW2 + 8192 * 2;
constexpr size_t OFF_SW4    = OFF_SW3 + 32768 * 2;
constexpr size_t OFF_WPT    = OFF_SW4 + 131072 * 2;
constexpr size_t OFF_SORT   = ((OFF_WPT + 60 * 512 * 4) + 255) & ~(size_t)255; // kB*kN float4

DI int cellof(float x) {
  int c = (int)(x * (float)GRD);
  return min(GRD - 1, max(0, c));
}
DI unsigned orderable(float f) {
  unsigned u = __float_as_uint(f);
  return (u & 0x80000000u) ? ~u : (u | 0x80000000u);
}

// =====================  zero the sync/count region  =====================
__global__ void k_zero(uint32_t* p, int nwords) {
  int i = blockIdx.x * blockDim.x + threadIdx.x;
  int st = gridDim.x * blockDim.x;
  for (; i < nwords; i += st) p[i] = 0u;
}

// =====================  weight prep: B-fragment swizzle (f16) + WpT  =====================
DI void swz(const float* __restrict__ W, _Float16* __restrict__ sw,
            int total, int nks, int Kreal, int N, int i0, int st) {
  for (int i = i0; i < total; i += st) {
    int j = i & 7, lane = (i >> 3) & 63, rest = i >> 9;
    int ks = rest % nks, nt = rest / nks;
    int k = ks * 32 + ((lane >> 4) << 3) + j;
    int n = nt * 16 + (lane & 15);
    sw[i] = (_Float16)((k < Kreal) ? W[k * N + n] : 0.f);
  }
}

__global__ void k_prep(const float* __restrict__ W1, const float* __restrict__ W2,
                       const float* __restrict__ W3, const float* __restrict__ W4,
                       const float* __restrict__ Wp,
                       _Float16* __restrict__ sw1, _Float16* __restrict__ sw2,
                       _Float16* __restrict__ sw3, _Float16* __restrict__ sw4,
                       float* __restrict__ wpt) {
  int i0 = blockIdx.x * blockDim.x + threadIdx.x;
  int st = gridDim.x * blockDim.x;
  swz(W1, sw1, 2048, 1, 6, 64, i0, st);
  swz(W2, sw2, 8192, 2, 64, 128, i0, st);
  swz(W3, sw3, 32768, 4, 128, 256, i0, st);
  swz(W4, sw4, 131072, 8, 256, 512, i0, st);
  for (int i = i0; i < 60 * 512; i += st) { int n = i >> 9, k = i & 511; wpt[i] = Wp[k * 60 + n]; }
}

// =====================  device-wide phase barrier (co-resident workers)  =====================
DI void gbar(uint32_t* ctr, unsigned target) {
  __syncthreads();
  if (threadIdx.x == 0) {
    __hip_atomic_fetch_add(ctr, 1u, __ATOMIC_ACQ_REL, __HIP_MEMORY_SCOPE_AGENT);
    long bail = 0;
    while (__hip_atomic_load(ctr, __ATOMIC_ACQUIRE, __HIP_MEMORY_SCOPE_AGENT) < target) {
      __builtin_amdgcn_s_sleep(32);
      if (++bail > 100000000L) break;
    }
  }
  __syncthreads();
}

// =====================  FPS: one block per batch, cell-granular bound-skip  ======
// Chunk == grid cell: analytically exact bounds (no bbox storage, no dilation).
// Serial chain intra-CU: bound test -> refine queued cells -> argmax -> publish.
// LDS (fps path, unioned with worker's 64KB cand):
//   [0,32768)       ckey u64[4096]      exact per-cell (maxdd | ~origidx)
//   [32768,49156)   lcs  u32[4097]      cstart copy
//   [49408,57600)   queue u16[4096]
//   [57664..)       misc: qn, warr[4], wslot
DI void fps_block(const float* __restrict__ xyz, float* __restrict__ outC,
                  u64* __restrict__ cline, uint32_t* __restrict__ gs,
                  const float4* __restrict__ sorted_g,
                  const uint32_t* __restrict__ cstart_g,
                  float* __restrict__ dd_g, int b, char* smem) {
  __builtin_amdgcn_s_setprio(3);
  const int tid = threadIdx.x;
  const int wave = tid >> 6, lane = tid & 63;
  const int grp = tid >> 4, lig = tid & 15;     // 16 groups x 16 lanes
  const float* X = xyz + (size_t)b * kN * 3;
  const float4* SP = sorted_g + (size_t)b * kN;
  float* DD = dd_g + (size_t)b * kN;
  u64* cl = cline + (size_t)b * kG * 16;

  u64* ckey = (u64*)smem;
  uint32_t* lcs = (uint32_t*)(smem + 32768);
  u16* queue = (u16*)(smem + 49408);
  int* qn = (int*)(smem + 57664);
  u64* warr = (u64*)(smem + 57672);
  float4* wslot = (float4*)(smem + 57712);

  float cx = X[0], cy = X[1], cz = X[2];
  if (tid == 0) {
    u64 tg = 1u;  // tag = it+1 for it=0
    __hip_atomic_store(cl + 0, ((u64)__float_as_uint(cx) << 32) | tg, __ATOMIC_RELAXED, __HIP_MEMORY_SCOPE_AGENT);
    __hip_atomic_store(cl + 1, ((u64)__float_as_uint(cy) << 32) | tg, __ATOMIC_RELAXED, __HIP_MEMORY_SCOPE_AGENT);
    __hip_atomic_store(cl + 2, ((u64)__float_as_uint(cz) << 32) | tg, __ATOMIC_RELAXED, __HIP_MEMORY_SCOPE_AGENT);
    outC[(size_t)b * kG * 3 + 0] = cx;
    outC[(size_t)b * kG * 3 + 1] = cy;
    outC[(size_t)b * kG * 3 + 2] = cz;
    // wait for workers' grid build (acquire)
    long bail = 0;
    while (__hip_atomic_load(gs + 2, __ATOMIC_ACQUIRE, __HIP_MEMORY_SCOPE_AGENT) < NWORK) {
      __builtin_amdgcn_s_sleep(16);
      if (++bail > 200000000L) break;
    }
    *qn = 0;
  }
  __syncthreads();
  for (int i = tid; i <= NCELL; i += 256) lcs[i] = cstart_g[(size_t)b * (NCELL + 1) + i];
  __syncthreads();

  for (int it = 1; it < kG; ++it) {
    // ---- Phase A: exact cell-box bound tests -> ballot-compressed queue ----
    if (it > 1) {
#pragma unroll
      for (int i = 0; i < NCELL / 256; ++i) {
        int c = (i << 8) + tid;
        float x0 = (float)(c & 15) * CW;
        float y0 = (float)((c >> 4) & 15) * CW;
        float z0 = (float)(c >> 8) * CW;
        float dx = fmaxf(fmaxf(x0 - cx, cx - (x0 + CW)), 0.f);
        float dy = fmaxf(fmaxf(y0 - cy, cy - (y0 + CW)), 0.f);
        float dz = fmaxf(fmaxf(z0 - cz, cz - (z0 + CW)), 0.f);
        float lb = dx * dx + dy * dy + dz * dz;
        float ub = __uint_as_float(((const uint32_t*)ckey)[2 * c + 1]);
        bool need = !(lb * 0.999f > ub);   // conservative: skip only when provably unchanged
        u64 m = __ballot(need);
        int base = 0;
        if (lane == 0) base = atomicAdd(qn, (int)__popcll(m));
        base = __shfl(base, 0);
        if (need) queue[base + (int)__popcll(m & ((1ull << lane) - 1ull))] = (u16)c;
      }
    }
    __syncthreads();
    // ---- Phase B: refine queued cells (16-lane group per cell, exact math) ----
    if (it == 1) {
      for (int c = grp; c < NCELL; c += 16) {
        int s0 = lcs[c], s1 = lcs[c + 1];
        u64 key = 0ull;
        for (int p = s0 + lig; p < s1; p += 16) {
          float4 pt = SP[p];
          float dx = __fsub_rn(pt.x, cx);
          float dy = __fsub_rn(pt.y, cy);
          float dz = __fsub_rn(pt.z, cz);
          float d = __fadd_rn(__fadd_rn(__fmul_rn(dx, dx), __fmul_rn(dy, dy)), __fmul_rn(dz, dz));
          float nd = fminf(1e10f, d);
          DD[p] = nd;
          u64 k = ((u64)__float_as_uint(nd) << 32) |
                  (u64)(0xFFFFFFFFu - (unsigned)__float_as_uint(pt.w));
          key = (k > key) ? k : key;
        }
#pragma unroll
        for (int off = 8; off; off >>= 1) {
          u64 o = __shfl_xor(key, off);
          key = (o > key) ? o : key;
        }
        if (lig == 0) ckey[c] = key;
      }
    } else {
      const int Q = *qn;
      for (int t = grp; t < Q; t += 16) {
        int c = (int)queue[t];
        int s0 = lcs[c], s1 = lcs[c + 1];
        u64 key = 0ull;
        for (int p = s0 + lig; p < s1; p += 16) {
          float4 pt = SP[p];
          float ddo = DD[p];
          float dx = __fsub_rn(pt.x, cx);
          float dy = __fsub_rn(pt.y, cy);
          float dz = __fsub_rn(pt.z, cz);
          float d = __fadd_rn(__fadd_rn(__fmul_rn(dx, dx), __fmul_rn(dy, dy)), __fmul_rn(dz, dz));
          float nd = fminf(ddo, d);
          DD[p] = nd;
          u64 k = ((u64)__float_as_uint(nd) << 32) |
                  (u64)(0xFFFFFFFFu - (unsigned)__float_as_uint(pt.w));
          key = (k > key) ? k : key;
        }
#pragma unroll
        for (int off = 8; off; off >>= 1) {
          u64 o = __shfl_xor(key, off);
          key = (o > key) ? o : key;
        }
        if (lig == 0) ckey[c] = key;
      }
    }
    __syncthreads();
    // ---- Phase C: argmax over 4096 exact cell keys (key embeds ~origidx) ----
    {
      u64 key = 0ull;
#pragma unroll
      for (int i = 0; i < NCELL / 256; ++i) {
        u64 k = ckey[(i << 8) + tid];
        key = (k > key) ? k : key;
      }
#pragma unroll
      for (int off = 32; off; off >>= 1) {
        u64 o = __shfl_xor(key, off);
        key = (o > key) ? o : key;
      }
      if (lane == 0) warr[wave] = key;
    }
    __syncthreads();
    // ---- Phase D: final reduce, coord gather, fire-and-forget publish ----
    if (tid == 0) {
      u64 k = warr[0];
#pragma unroll
      for (int i = 1; i < 4; ++i) k = (warr[i] > k) ? warr[i] : k;
      unsigned wi = 0xFFFFFFFFu - (unsigned)(k & 0xFFFFFFFFu);
      float wx = X[3 * wi], wy = X[3 * wi + 1], wz = X[3 * wi + 2];
      *wslot = make_float4(wx, wy, wz, 0.f);
      u64 tg = (unsigned)(it + 1);
      u64* e = cl + (size_t)it * 16;
      __hip_atomic_store(e + 0, ((u64)__float_as_uint(wx) << 32) | tg, __ATOMIC_RELAXED, __HIP_MEMORY_SCOPE_AGENT);
      __hip_atomic_store(e + 1, ((u64)__float_as_uint(wy) << 32) | tg, __ATOMIC_RELAXED, __HIP_MEMORY_SCOPE_AGENT);
      __hip_atomic_store(e + 2, ((u64)__float_as_uint(wz) << 32) | tg, __ATOMIC_RELAXED, __HIP_MEMORY_SCOPE_AGENT);
      outC[((size_t)b * kG + it) * 3 + 0] = wx;
      outC[((size_t)b * kG + it) * 3 + 1] = wy;
      outC[((size_t)b * kG + it) * 3 + 2] = wz;
      *qn = 0;
    }
    __syncthreads();
    float4 wc = *wslot;
    cx = wc.x; cy = wc.y; cz = wc.z;
  }
}

// =====================  bitonic sort (shared, 256 threads)  =====================
DI void bitonic(u64* a, int n, int tid) {
  for (int k = 2; k <= n; k <<= 1)
    for (int j = k >> 1; j > 0; j >>= 1) {
      __syncthreads();
      for (int i = tid; i < n; i += 256) {
        int ix = i ^ j;
        if (ix > i) {
          u64 x = a[i], y = a[ix];
          bool up = ((i & k) == 0);
          if ((x > y) == up) { a[i] = y; a[ix] = x; }
        }
      }
    }
  __syncthreads();
}

// =====================  MLP layers (f16 MFMA)  =====================
template <int Kdim, int Ndim, int SIN, int SOUT>
DI void mfma_layer(const _Float16* __restrict__ Xin, _Float16* __restrict__ Xout,
                   const _Float16* __restrict__ Wsw, const float* __restrict__ bias,
                   int wave, int lane) {
  constexpr int NKS = Kdim / 32;
  constexpr int NTW = Ndim / 64;
  constexpr int CH = (NTW < 4) ? NTW : 4;
  const int quad = lane >> 4, l16 = lane & 15;
  for (int c0 = 0; c0 < NTW; c0 += CH) {
    f32x4 acc[CH][4];
#pragma unroll
    for (int nt = 0; nt < CH; ++nt) {
      float bv = bias[wave * (Ndim / 4) + (c0 + nt) * 16 + l16];
#pragma unroll
      for (int m = 0; m < 4; ++m) acc[nt][m] = {bv, bv, bv, bv};
    }
#pragma unroll
    for (int ks = 0; ks < NKS; ++ks) {
      f16x8 af[4];
#pragma unroll
      for (int m = 0; m < 4; ++m)
        af[m] = *(const f16x8*)(Xin + (m * 16 + l16) * SIN + ks * 32 + quad * 8);
#pragma unroll
      for (int nt = 0; nt < CH; ++nt) {
        int ntg = wave * NTW + c0 + nt;
        f16x8 bf = *(const f16x8*)(Wsw + ((size_t)(ntg * NKS + ks) * 64 + lane) * 8);
#pragma unroll
        for (int m = 0; m < 4; ++m)
          acc[nt][m] = __builtin_amdgcn_mfma_f32_16x16x32_f16(af[m], bf, acc[nt][m], 0, 0, 0);
      }
    }
#pragma unroll
    for (int nt = 0; nt < CH; ++nt) {
      int col = wave * (Ndim / 4) + (c0 + nt) * 16 + l16;
#pragma unroll
      for (int m = 0; m < 4; ++m)
#pragma unroll
        for (int r = 0; r < 4; ++r) {
          int row = m * 16 + quad * 4 + r;
          Xout[row * SOUT + col] = (_Float16)fmaxf(acc[nt][m][r], 0.f);
        }
    }
  }
}

DI void mfma_layer4(const _Float16* __restrict__ Xin, const _Float16* __restrict__ Wsw,
                    const float* __restrict__ bias, float* __restrict__ maxv,
                    int wave, int lane) {
  constexpr int SIN = 264, NKS = 8, NTW = 8, CH = 4;
  const int quad = lane >> 4, l16 = lane & 15;
  for (int c0 = 0; c0 < NTW; c0 += CH) {
    f32x4 acc[CH][4];
#pragma unroll
    for (int nt = 0; nt < CH; ++nt) {
      float bv = bias[wave * 128 + (c0 + nt) * 16 + l16];
#pragma unroll
      for (int m = 0; m < 4; ++m) acc[nt][m] = {bv, bv, bv, bv};
    }
#pragma unroll
    for (int ks = 0; ks < NKS; ++ks) {
      f16x8 af[4];
#pragma unroll
      for (int m = 0; m < 4; ++m)
        af[m] = *(const f16x8*)(Xin + (m * 16 + l16) * SIN + ks * 32 + quad * 8);
#pragma unroll
      for (int nt = 0; nt < CH; ++nt) {
        int ntg = wave * NTW + c0 + nt;
        f16x8 bf = *(const f16x8*)(Wsw + ((size_t)(ntg * NKS + ks) * 64 + lane) * 8);
#pragma unroll
        for (int m = 0; m < 4; ++m)
          acc[nt][m] = __builtin_amdgcn_mfma_f32_16x16x32_f16(af[m], bf, acc[nt][m], 0, 0, 0);
      }
    }
#pragma unroll
    for (int nt = 0; nt < CH; ++nt) {
      float mx = 0.f;  // relu folded into max
#pragma unroll
      for (int m = 0; m < 4; ++m)
#pragma unroll
        for (int r = 0; r < 4; ++r) mx = fmaxf(mx, acc[nt][m][r]);
      mx = fmaxf(mx, __shfl_xor(mx, 16, 64));
      mx = fmaxf(mx, __shfl_xor(mx, 32, 64));
      if (quad == 0) maxv[wave * 128 + (c0 + nt) * 16 + l16] = mx;
    }
  }
}

// =====================  fused kernel  =====================
__global__ __launch_bounds__(256, 2) void k_fused(
    const float* __restrict__ xyz, const float* __restrict__ color,
    float* __restrict__ outC, float* __restrict__ outE,
    u64* __restrict__ cline, uint32_t* __restrict__ ccnt,
    uint32_t* __restrict__ cstart, uint32_t* __restrict__ cur,
    float4* __restrict__ sorted, float* __restrict__ dd_g,
    uint32_t* __restrict__ gs,
    const _Float16* __restrict__ sw1, const _Float16* __restrict__ sw2,
    const _Float16* __restrict__ sw3, const _Float16* __restrict__ sw4,
    const float* __restrict__ wpt,
    const float* __restrict__ b1, const float* __restrict__ b2,
    const float* __restrict__ b3, const float* __restrict__ b4,
    const float* __restrict__ bp) {
  __shared__ __align__(16) char smem[65536];
  const int bi = blockIdx.x;
  if (bi < kB) {  // FPS block for batch bi
    fps_block(xyz, outC, cline, gs, sorted, cstart, dd_g, bi, smem);
    return;
  }
  if (bi >= 256 && bi < 256 + kB) return;  // dummy: frees second slot of FPS CUs

  // ---------------- worker block ----------------
  const int wj = (bi < 256) ? (bi - kB) : (bi - 8);  // 0..503
  const int tid = threadIdx.x;
  const int wave = tid >> 6, lane = tid & 63;
  __shared__ int nC;
  __shared__ float4 spc;
  __shared__ uint32_t s_part[256];
  u64* cand = (u64*)smem;

  // ---- grid build (single 16^3 grid for KNN + FPS) ----
  for (int i = wj * 256 + tid; i < kB * kN; i += NWORK * 256) {
    int b = i >> 16, p = i & (kN - 1);
    const float* q = xyz + ((size_t)b * kN + p) * 3;
    int cid = (cellof(q[2]) * GRD + cellof(q[1])) * GRD + cellof(q[0]);
    atomicAdd(&ccnt[b * NCELL + cid], 1u);
  }
  gbar(gs + 0, NWORK);
  if (wj < kB) {
    int b = wj;
    const uint32_t* cc = ccnt + (size_t)b * NCELL;
    uint32_t* cs = cstart + (size_t)b * (NCELL + 1);
    uint32_t* cu = cur + (size_t)b * NCELL;
    const int chunk = NCELL / 256;   // 16
    int c0 = tid * chunk;
    uint32_t s = 0;
    for (int i = 0; i < chunk; ++i) s += cc[c0 + i];
    s_part[tid] = s;
    __syncthreads();
    for (int off = 1; off < 256; off <<= 1) {
      uint32_t add = (tid >= off) ? s_part[tid - off] : 0u;
      __syncthreads();
      s_part[tid] += add;
      __syncthreads();
    }
    uint32_t run = s_part[tid] - s;
    for (int i = 0; i < chunk; ++i) {
      int c = c0 + i;
      cs[c] = run; cu[c] = run; run += cc[c];
    }
    if (tid == 255) cs[NCELL] = run;
  }
  gbar(gs + 1, NWORK);
  for (int i = wj * 256 + tid; i < kB * kN; i += NWORK * 256) {
    int b = i >> 16, p = i & (kN - 1);
    const float* q = xyz + ((size_t)b * kN + p) * 3;
    float x = q[0], y = q[1], z = q[2];
    int cid = (cellof(z) * GRD + cellof(y)) * GRD + cellof(x);
    uint32_t pos = atomicAdd(&cur[b * NCELL + cid], 1u);
    sorted[(size_t)b * kN + pos] = make_float4(x, y, z, __uint_as_float((unsigned)p));
  }
  gbar(gs + 2, NWORK);   // FPS blocks wait on this counter

  // ---- consume groups in production order: job j = it*4 + b ----
  for (int j = wj; j < kB * kG; j += NWORK) {
    const int it = j >> 2, b = j & 3;
    if (tid < 64) {
      const u64* e = cline + ((size_t)b * kG + it) * 16;
      u64 v = 0; long bail = 0;
      for (;;) {
        if (lane < 3)
          v = __hip_atomic_load(e + lane, __ATOMIC_RELAXED, __HIP_MEMORY_SCOPE_AGENT);
        bool ok = (lane >= 3) || ((unsigned)v == (unsigned)(it + 1));
        if (__all(ok)) break;
        __builtin_amdgcn_s_sleep(8);
        if (++bail > 100000000L) break;
      }
      u64 v0 = __shfl(v, 0), v1 = __shfl(v, 1), v2 = __shfl(v, 2);
      if (tid == 0)
        spc = make_float4(__uint_as_float((unsigned)(v0 >> 32)),
                          __uint_as_float((unsigned)(v1 >> 32)),
                          __uint_as_float((unsigned)(v2 >> 32)), 0.f);
    }
    __syncthreads();
    const float cx = spc.x, cy = spc.y, cz = spc.z;

    // ---- KNN (expanding box + exact re-rank + bitonic) ----
    const float nc = __fadd_rn(__fadd_rn(__fmul_rn(cx, cx), __fmul_rn(cy, cy)), __fmul_rn(cz, cz));
    const float4* SPb = sorted + (size_t)b * kN;
    const uint32_t* CS = cstart + (size_t)b * (NCELL + 1);
    const int ccx = cellof(cx), ccy = cellof(cy), ccz = cellof(cz);
    if (tid == 0) nC = 0;
    __syncthreads();
    int plox = 1, phix = 0, ploy = 1, phiy = 0, ploz = 1, phiz = 0;
    for (int r = 1; r <= GRD; ++r) {
      int lox = max(0, ccx - r), hix = min(GRD - 1, ccx + r);
      int loy = max(0, ccy - r), hiy = min(GRD - 1, ccy + r);
      int loz = max(0, ccz - r), hiz = min(GRD - 1, ccz + r);
      for (int z = loz; z <= hiz; ++z)
        for (int y = loy; y <= hiy; ++y) {
          bool rowPrev = (r > 1) && (z >= ploz && z <= phiz && y >= ploy && y <= phiy);
          for (int s = 0; s < 2; ++s) {
            int xa, xb;
            if (!rowPrev) { if (s) break; xa = lox; xb = hix; }
            else if (s == 0) { xa = lox; xb = plox - 1; }
            else { xa = phix + 1; xb = hix; }
            if (xa > xb) continue;
            int c0 = (z * GRD + y) * GRD + xa;
            int i0 = CS[c0];
            int i1 = CS[(z * GRD + y) * GRD + xb + 1];
            for (int i = i0 + tid; i < i1; i += 256) {
              float4 pt = SPb[i];
              float npn = __fadd_rn(__fadd_rn(__fmul_rn(pt.x, pt.x), __fmul_rn(pt.y, pt.y)),
                                    __fmul_rn(pt.z, pt.z));
              float dot = __fadd_rn(__fadd_rn(__fmul_rn(cx, pt.x), __fmul_rn(cy, pt.y)),
                                    __fmul_rn(cz, pt.z));
              float sq = __fsub_rn(__fadd_rn(nc, npn), __fmul_rn(2.0f, dot));
              unsigned key = orderable(sq);
              int pos = atomicAdd(&nC, 1);
              if (pos < 8192)
                cand[pos] = ((u64)key << 32) | (unsigned)__float_as_uint(pt.w);
            }
          }
        }
      __syncthreads();
      int n = min(nC, 8192);
      float rc = 1e30f;
      if (lox > 0) rc = fminf(rc, cx - (float)lox * CW);
      if (hix < GRD - 1) rc = fminf(rc, (float)(hix + 1) * CW - cx);
      if (loy > 0) rc = fminf(rc, cy - (float)loy * CW);
      if (hiy < GRD - 1) rc = fminf(rc, (float)(hiy + 1) * CW - cy);
      if (loz > 0) rc = fminf(rc, cz - (float)loz * CW);
      if (hiz < GRD - 1) rc = fminf(rc, (float)(hiz + 1) * CW - cz);
      float r2 = (rc >= 1e29f) ? 3.0e38f : rc * rc * (1.0f - 1e-5f);
      unsigned keyR = orderable(r2);
      bool done = false;
      if (n >= kM) {
        int np2 = 1;
        while (np2 < n) np2 <<= 1;
        for (int i = n + tid; i < np2; i += 256) cand[i] = ~0ull;
        bitonic(cand, np2, tid);
        unsigned k63 = (unsigned)(cand[kM - 1] >> 32);
        done = (k63 <= keyR);
        if (tid == 0) nC = n;
      }
      __syncthreads();
      if (done) break;
      plox = lox; phix = hix; ploy = loy; phiy = hiy; ploz = loz; phiz = hiz;
    }

    // ---- MLP (reuses smem; neighbor indices straight from cand) ----
    uint32_t pidx = 0;
    if (tid < kM) pidx = (uint32_t)(cand[tid] & 0xFFFFFFFFu);
    __syncthreads();
    _Float16* bufA = (_Float16*)smem;
    _Float16* bufB = (_Float16*)(smem + 17408);
    float* maxv = (float*)smem;
    float* psum = (float*)(smem + 2048);
    if (tid < kM) {
      const float* xp = xyz + ((size_t)b * kN + pidx) * 3;
      const float* cp = color + ((size_t)b * kN + pidx) * 3;
      f16x8 v = {};
      v[0] = (_Float16)__fsub_rn(xp[0], cx);
      v[1] = (_Float16)__fsub_rn(xp[1], cy);
      v[2] = (_Float16)__fsub_rn(xp[2], cz);
      v[3] = (_Float16)cp[0];
      v[4] = (_Float16)cp[1];
      v[5] = (_Float16)cp[2];
      f16x8 zf = {};
      *(f16x8*)(bufA + tid * 40 + 0) = v;
      *(f16x8*)(bufA + tid * 40 + 8) = zf;
      *(f16x8*)(bufA + tid * 40 + 16) = zf;
      *(f16x8*)(bufA + tid * 40 + 24) = zf;
    }
    __syncthreads();
    mfma_layer<32, 64, 40, 72>(bufA, bufB, sw1, b1, wave, lane);
    __syncthreads();
    mfma_layer<64, 128, 72, 136>(bufB, bufA, sw2, b2, wave, lane);
    __syncthreads();
    mfma_layer<128, 256, 136, 264>(bufA, bufB, sw3, b3, wave, lane);
    __syncthreads();
    mfma_layer4(bufB, sw4, b4, maxv, wave, lane);
    __syncthreads();
    if (tid < 240) {
      int jj = tid >> 2, q = tid & 3;
      const float* w = wpt + (size_t)jj * 512 + q * 128;
      float s = 0.f;
#pragma unroll 4
      for (int k = 0; k < 128; ++k) s = fmaf(maxv[q * 128 + k], w[k], s);
      psum[tid] = s;
    }
    __syncthreads();
    if (tid < kE) {
      float e = __fadd_rn(__fadd_rn(psum[tid * 4 + 0], psum[tid * 4 + 1]),
                          __fadd_rn(psum[tid * 4 + 2], psum[tid * 4 + 3])) + bp[tid];
      outE[((size_t)b * kG + it) * kE + tid] = e;
    }
    __syncthreads();  // smem reuse fence before next job
  }
}

// =====================  launch  =====================
extern "C" void kernel_launch(void* const* d_in, const int* in_sizes, int n_in,
                              void* d_out, int out_size, void* d_ws, size_t ws_size,
                              hipStream_t stream) {
  (void)in_sizes; (void)n_in; (void)out_size; (void)ws_size;
  const float* xyz = (const float*)d_in[0];
  const float* color = (const float*)d_in[1];
  const float* W1 = (const float*)d_in[2];
  const float* b1 = (const float*)d_in[3];
  const float* W2 = (const float*)d_in[4];
  const float* b2 = (const float*)d_in[5];
  const float* W3 = (const float*)d_in[6];
  const float* b3 = (const float*)d_in[7];
  const float* W4 = (const float*)d_in[8];
  const float* b4 = (const float*)d_in[9];
  const float* Wp = (const float*)d_in[10];
  const float* bp = (const float*)d_in[11];

  char* ws = (char*)d_ws;
  auto cline = (u64*)(ws + OFF_CLINE);
  auto ccnt = (uint32_t*)(ws + OFF_CCNT);
  auto gs = (uint32_t*)(ws + OFF_GS);
  auto cstart = (uint32_t*)(ws + OFF_CSTART);
  auto cur = (uint32_t*)(ws + OFF_CUR);
  auto dd = (float*)(ws + OFF_DD);
  auto sw1 = (_Float16*)(ws + OFF_SW1);
  auto sw2 = (_Float16*)(ws + OFF_SW2);
  auto sw3 = (_Float16*)(ws + OFF_SW3);
  auto sw4 = (_Float16*)(ws + OFF_SW4);
  auto wpt = (float*)(ws + OFF_WPT);
  auto sorted = (float4*)(ws + OFF_SORT);

  float* outE = (float*)d_out;
  float* outC = outE + (size_t)kB * kG * kE;

  k_zero<<<256, 256, 0, stream>>>((uint32_t*)ws, (int)(ZERO_BYTES / 4));
  k_prep<<<256, 256, 0, stream>>>(W1, W2, W3, W4, Wp, sw1, sw2, sw3, sw4, wpt);
  k_fused<<<NBLK, 256, 0, stream>>>(xyz, color, outC, outE, cline, ccnt, cstart,
                                    cur, sorted, dd, gs, sw1, sw2, sw3, sw4, wpt,
                                    b1, b2, b3, b4, bp);
}

// Round 7
// 2010.129 us; speedup vs baseline: 3.1838x; 2.1970x over previous
//
#include <hip/hip_runtime.h>
#include <stdint.h>

#define DI __device__ __forceinline__

typedef _Float16 f16x8 __attribute__((ext_vector_type(8)));
typedef float f32x4 __attribute__((ext_vector_type(4)));
typedef unsigned long long u64;
typedef unsigned short u16;

// ---- problem constants ----
constexpr int kB = 4;
constexpr int kN = 65536;
constexpr int kG = 512;   // NUM_GROUP
constexpr int kM = 64;    // GROUP_SIZE
constexpr int kE = 60;    // EMB
constexpr int GRD = 16;   // unified grid resolution (FPS chunks == cells)
constexpr int NCELL = GRD * GRD * GRD;   // 4096
constexpr int NSUP = 512;                // 8x8x8 super-cells (2x2x2 cells each)
constexpr float CW = 1.0f / 16.0f;

constexpr int TPB = 512;    // threads per block (8 waves)
constexpr int NWORK = 252;  // worker blocks
constexpr int NBLK = 256;   // 4 fps + 252 workers, 1 block/CU -> all co-resident

// ---- workspace layout (bytes) ----
// cline per (b,it): 128B line, 3 tagged words: (coord_bits<<32)|(it+1). 1 writer.
constexpr size_t OFF_CLINE  = 0;
constexpr size_t OFF_CCNT   = OFF_CLINE + (size_t)kB * kG * 128;
constexpr size_t OFF_GS     = OFF_CCNT + (size_t)kB * NCELL * 4;
constexpr size_t ZERO_BYTES = OFF_GS + 64;
constexpr size_t OFF_CSTART = (ZERO_BYTES + 255) & ~(size_t)255;   // kB*(NCELL+1) u32
constexpr size_t OFF_CUR    = OFF_CSTART + (size_t)kB * (NCELL + 1) * 4;
constexpr size_t OFF_DD     = ((OFF_CUR + (size_t)kB * NCELL * 4) + 255) & ~(size_t)255;
constexpr size_t OFF_SW1    = (OFF_DD + (size_t)kB * kN * 4 + 255) & ~(size_t)255;
constexpr size_t OFF_SW2    = OFF_SW1 + 2048 * 2;
constexpr size_t OFF_SW3    = OFF_SW2 + 8192 * 2;
constexpr size_t OFF_SW4    = OFF_SW3 + 32768 * 2;
constexpr size_t OFF_WPT    = OFF_SW4 + 131072 * 2;
constexpr size_t OFF_SORT   = ((OFF_WPT + 60 * 512 * 4) + 255) & ~(size_t)255; // kB*kN float4

DI int cellof(float x) {
  int c = (int)(x * (float)GRD);
  return min(GRD - 1, max(0, c));
}
DI unsigned orderable(float f) {
  unsigned u = __float_as_uint(f);
  return (u & 0x80000000u) ? ~u : (u | 0x80000000u);
}

// =====================  zero the sync/count region  =====================
__global__ void k_zero(uint32_t* p, int nwords) {
  int i = blockIdx.x * blockDim.x + threadIdx.x;
  int st = gridDim.x * blockDim.x;
  for (; i < nwords; i += st) p[i] = 0u;
}

// =====================  weight prep: B-fragment swizzle (f16) + WpT  =====================
DI void swz(const float* __restrict__ W, _Float16* __restrict__ sw,
            int total, int nks, int Kreal, int N, int i0, int st) {
  for (int i = i0; i < total; i += st) {
    int j = i & 7, lane = (i >> 3) & 63, rest = i >> 9;
    int ks = rest % nks, nt = rest / nks;
    int k = ks * 32 + ((lane >> 4) << 3) + j;
    int n = nt * 16 + (lane & 15);
    sw[i] = (_Float16)((k < Kreal) ? W[k * N + n] : 0.f);
  }
}

__global__ void k_prep(const float* __restrict__ W1, const float* __restrict__ W2,
                       const float* __restrict__ W3, const float* __restrict__ W4,
                       const float* __restrict__ Wp,
                       _Float16* __restrict__ sw1, _Float16* __restrict__ sw2,
                       _Float16* __restrict__ sw3, _Float16* __restrict__ sw4,
                       float* __restrict__ wpt) {
  int i0 = blockIdx.x * blockDim.x + threadIdx.x;
  int st = gridDim.x * blockDim.x;
  swz(W1, sw1, 2048, 1, 6, 64, i0, st);
  swz(W2, sw2, 8192, 2, 64, 128, i0, st);
  swz(W3, sw3, 32768, 4, 128, 256, i0, st);
  swz(W4, sw4, 131072, 8, 256, 512, i0, st);
  for (int i = i0; i < 60 * 512; i += st) { int n = i >> 9, k = i & 511; wpt[i] = Wp[k * 60 + n]; }
}

// =====================  device-wide phase barrier (co-resident workers)  =====================
DI void gbar(uint32_t* ctr, unsigned target) {
  __syncthreads();
  if (threadIdx.x == 0) {
    __hip_atomic_fetch_add(ctr, 1u, __ATOMIC_ACQ_REL, __HIP_MEMORY_SCOPE_AGENT);
    long bail = 0;
    while (__hip_atomic_load(ctr, __ATOMIC_ACQUIRE, __HIP_MEMORY_SCOPE_AGENT) < target) {
      __builtin_amdgcn_s_sleep(32);
      if (++bail > 100000000L) break;
    }
  }
  __syncthreads();
}

// =====================  FPS cell refine (4-lane group, batched loads)  ======
template <bool FIRST>
DI u64 refine_cell(int c, const float4* __restrict__ SP, float* __restrict__ DD,
                   const uint32_t* __restrict__ lcs,
                   float cx, float cy, float cz, int lig) {
  int s0 = (int)lcs[c], s1 = (int)lcs[c + 1];
  int pbase = s0 + lig;
  float4 pt[8];
  float ddo[8];
#pragma unroll
  for (int j = 0; j < 8; ++j) {
    int p = pbase + 4 * j;
    int pc = max(min(p, s1 - 1), 0);
    pt[j] = SP[pc];
    ddo[j] = FIRST ? 1e10f : DD[pc];
  }
  u64 key = 0ull;
#pragma unroll
  for (int j = 0; j < 8; ++j) {
    int p = pbase + 4 * j;
    if (p < s1) {
      float dx = __fsub_rn(pt[j].x, cx);
      float dy = __fsub_rn(pt[j].y, cy);
      float dz = __fsub_rn(pt[j].z, cz);
      float d = __fadd_rn(__fadd_rn(__fmul_rn(dx, dx), __fmul_rn(dy, dy)), __fmul_rn(dz, dz));
      float nd = fminf(ddo[j], d);
      DD[p] = nd;
      u64 k = ((u64)__float_as_uint(nd) << 32) |
              (u64)(0xFFFFFFFFu - (unsigned)__float_as_uint(pt[j].w));
      key = (k > key) ? k : key;
    }
  }
  // rare tail: cells with more than 32 points (Poisson(16) tail)
  for (int p = pbase + 32; p < s1; p += 4) {
    float4 pp = SP[p];
    float od = FIRST ? 1e10f : DD[p];
    float dx = __fsub_rn(pp.x, cx);
    float dy = __fsub_rn(pp.y, cy);
    float dz = __fsub_rn(pp.z, cz);
    float d = __fadd_rn(__fadd_rn(__fmul_rn(dx, dx), __fmul_rn(dy, dy)), __fmul_rn(dz, dz));
    float nd = fminf(od, d);
    DD[p] = nd;
    u64 k = ((u64)__float_as_uint(nd) << 32) |
            (u64)(0xFFFFFFFFu - (unsigned)__float_as_uint(pp.w));
    key = (k > key) ? k : key;
  }
  u64 o = __shfl_xor(key, 1); key = (o > key) ? o : key;
  o = __shfl_xor(key, 2); key = (o > key) ? o : key;
  return key;
}

// =====================  FPS: one 512-thread block per batch  ===========
// LDS layout (fps path; unioned with worker's 64KB cand):
//   [0,32768)       ckey u64[4096]      exact per-cell (maxdd | ~origidx)
//   [32768,49156)   lcs  u32[4097]
//   [49408,57600)   queue u16[4096]
//   [57600,58624)   squeue u16[512]
//   [58624,60672)   skey32 u32[512]     hi-32 of super max key
//   [60672..)       misc: qn, qsn, warr u64[8], wbuf float4[4]
DI void fps_block(const float* __restrict__ xyz, float* __restrict__ outC,
                  u64* __restrict__ cline, uint32_t* __restrict__ gs,
                  const float4* __restrict__ sorted_g,
                  const uint32_t* __restrict__ cstart_g,
                  float* __restrict__ dd_g, int b, char* smem) {
  __builtin_amdgcn_s_setprio(3);
  const int tid = threadIdx.x;
  const int wv = tid >> 6, lane = tid & 63;
  const int grp4 = tid >> 2, lig = tid & 3;
  const float* X = xyz + (size_t)b * kN * 3;
  const float4* SP = sorted_g + (size_t)b * kN;
  float* DD = dd_g + (size_t)b * kN;
  u64* cl = cline + (size_t)b * kG * 16;

  u64* ckey = (u64*)smem;
  uint32_t* lcs = (uint32_t*)(smem + 32768);
  u16* queue = (u16*)(smem + 49408);
  u16* squeue = (u16*)(smem + 57600);
  uint32_t* skey32 = (uint32_t*)(smem + 58624);
  int* qn = (int*)(smem + 60672);
  int* qsn = (int*)(smem + 60676);
  u64* warr = (u64*)(smem + 60736);
  float4* wbuf = (float4*)(smem + 60800);

  float cx = X[0], cy = X[1], cz = X[2];
  if (tid == 0) {
    u64 tg = 1u;  // tag = it+1 for it=0
    __hip_atomic_store(cl + 0, ((u64)__float_as_uint(cx) << 32) | tg, __ATOMIC_RELAXED, __HIP_MEMORY_SCOPE_AGENT);
    __hip_atomic_store(cl + 1, ((u64)__float_as_uint(cy) << 32) | tg, __ATOMIC_RELAXED, __HIP_MEMORY_SCOPE_AGENT);
    __hip_atomic_store(cl + 2, ((u64)__float_as_uint(cz) << 32) | tg, __ATOMIC_RELAXED, __HIP_MEMORY_SCOPE_AGENT);
    outC[(size_t)b * kG * 3 + 0] = cx;
    outC[(size_t)b * kG * 3 + 1] = cy;
    outC[(size_t)b * kG * 3 + 2] = cz;
    long bail = 0;   // wait for workers' grid build (acquire)
    while (__hip_atomic_load(gs + 2, __ATOMIC_ACQUIRE, __HIP_MEMORY_SCOPE_AGENT) < NWORK) {
      __builtin_amdgcn_s_sleep(16);
      if (++bail > 200000000L) break;
    }
    *qn = 0; *qsn = 0;
  }
  __syncthreads();
  for (int i = tid; i <= NCELL; i += TPB) lcs[i] = cstart_g[(size_t)b * (NCELL + 1) + i];
  __syncthreads();

  for (int it = 1; it < kG; ++it) {
    if (it > 1) {
      // ---- Phase A1: super-cell bound tests -> squeue ----
      {
        int s = tid;  // 512 supers == TPB
        int sx = s & 7, sy = (s >> 3) & 7, sz = s >> 6;
        float x0 = (float)sx * (2.f * CW);
        float y0 = (float)sy * (2.f * CW);
        float z0 = (float)sz * (2.f * CW);
        float dx = fmaxf(fmaxf(x0 - cx, cx - (x0 + 2.f * CW)), 0.f);
        float dy = fmaxf(fmaxf(y0 - cy, cy - (y0 + 2.f * CW)), 0.f);
        float dz = fmaxf(fmaxf(z0 - cz, cz - (z0 + 2.f * CW)), 0.f);
        float lb = dx * dx + dy * dy + dz * dz;
        bool need = !(lb * 0.999f > __uint_as_float(skey32[s]));
        u64 m = __ballot(need);
        int base = 0;
        if (lane == 0) base = atomicAdd(qsn, (int)__popcll(m));
        base = __shfl(base, 0);
        if (need) squeue[base + (int)__popcll(m & ((1ull << lane) - 1ull))] = (u16)s;
      }
      __syncthreads();
      // ---- Phase A2: expand queued supers -> cell queue ----
      {
        const int Qs = *qsn;
        int g8 = lane >> 3, lig8 = lane & 7;
        for (int t0 = 0; t0 < Qs; t0 += 64) {
          int t = t0 + wv * 8 + g8;
          bool act = t < Qs;
          int ss = act ? (int)squeue[t] : 0;
          int sx = ss & 7, sy = (ss >> 3) & 7, sz = ss >> 6;
          int cxi = 2 * sx + (lig8 & 1);
          int cyi = 2 * sy + ((lig8 >> 1) & 1);
          int czi = 2 * sz + (lig8 >> 2);
          int c = (czi * GRD + cyi) * GRD + cxi;
          float x0 = (float)cxi * CW, y0 = (float)cyi * CW, z0 = (float)czi * CW;
          float dx = fmaxf(fmaxf(x0 - cx, cx - (x0 + CW)), 0.f);
          float dy = fmaxf(fmaxf(y0 - cy, cy - (y0 + CW)), 0.f);
          float dz = fmaxf(fmaxf(z0 - cz, cz - (z0 + CW)), 0.f);
          float lb = dx * dx + dy * dy + dz * dz;
          float ub = __uint_as_float(((const uint32_t*)ckey)[2 * c + 1]);
          bool need = act && !(lb * 0.999f > ub);
          u64 m = __ballot(need);
          int base = 0;
          if (lane == 0) base = atomicAdd(qn, (int)__popcll(m));
          base = __shfl(base, 0);
          if (need) queue[base + (int)__popcll(m & ((1ull << lane) - 1ull))] = (u16)c;
        }
      }
    }
    __syncthreads();
    // ---- Phase B: refine (128 four-lane groups) ----
    if (it == 1) {
      for (int c = grp4; c < NCELL; c += 128) {
        u64 key = refine_cell<true>(c, SP, DD, lcs, cx, cy, cz, lig);
        if (lig == 0) ckey[c] = key;
      }
    } else {
      const int Q = *qn;
      for (int t = grp4; t < Q; t += 128) {
        int c = (int)queue[t];
        u64 key = refine_cell<false>(c, SP, DD, lcs, cx, cy, cz, lig);
        if (lig == 0) ckey[c] = key;
      }
    }
    __syncthreads();
    // ---- Phase C: super max + block argmax (fused scan over all 4096 cells) ----
    {
      int s = tid;
      int sx = s & 7, sy = (s >> 3) & 7, sz = s >> 6;
      u64 smax = 0ull;
#pragma unroll
      for (int d = 0; d < 8; ++d) {
        int cxi = 2 * sx + (d & 1);
        int cyi = 2 * sy + ((d >> 1) & 1);
        int czi = 2 * sz + (d >> 2);
        u64 k = ckey[(czi * GRD + cyi) * GRD + cxi];
        smax = (k > smax) ? k : smax;
      }
      skey32[s] = (uint32_t)(smax >> 32);
      u64 key = smax;
#pragma unroll
      for (int off = 32; off; off >>= 1) {
        u64 o = __shfl_xor(key, off);
        key = (o > key) ? o : key;
      }
      if (lane == 0) warr[wv] = key;
    }
    __syncthreads();
    // ---- Phase D: final reduce, coord gather, buffer winner ----
    if (tid == 0) {
      u64 k = warr[0];
#pragma unroll
      for (int i = 1; i < 8; ++i) k = (warr[i] > k) ? warr[i] : k;
      unsigned wi = 0xFFFFFFFFu - (unsigned)(k & 0xFFFFFFFFu);
      wbuf[it & 3] = make_float4(X[3 * wi], X[3 * wi + 1], X[3 * wi + 2], 0.f);
      *qn = 0; *qsn = 0;
    }
    __syncthreads();
    float4 wc = wbuf[it & 3];
    cx = wc.x; cy = wc.y; cz = wc.z;
    // batched fire-and-forget publish every 4 rounds (amortizes store drain)
    if ((it & 3) == 3 || it == kG - 1) {
      int k0 = it & ~3;
      if (tid <= (it & 3) && (k0 + tid) >= 1) {
        int itp = k0 + tid;
        float4 w = wbuf[tid];
        u64 tg = (unsigned)(itp + 1);
        u64* e = cl + (size_t)itp * 16;
        __hip_atomic_store(e + 0, ((u64)__float_as_uint(w.x) << 32) | tg, __ATOMIC_RELAXED, __HIP_MEMORY_SCOPE_AGENT);
        __hip_atomic_store(e + 1, ((u64)__float_as_uint(w.y) << 32) | tg, __ATOMIC_RELAXED, __HIP_MEMORY_SCOPE_AGENT);
        __hip_atomic_store(e + 2, ((u64)__float_as_uint(w.z) << 32) | tg, __ATOMIC_RELAXED, __HIP_MEMORY_SCOPE_AGENT);
        outC[((size_t)b * kG + itp) * 3 + 0] = w.x;
        outC[((size_t)b * kG + itp) * 3 + 1] = w.y;
        outC[((size_t)b * kG + itp) * 3 + 2] = w.z;
      }
    }
  }
}

// =====================  bitonic sort (shared, 512 threads)  =====================
DI void bitonic(u64* a, int n, int tid) {
  for (int k = 2; k <= n; k <<= 1)
    for (int j = k >> 1; j > 0; j >>= 1) {
      __syncthreads();
      for (int i = tid; i < n; i += TPB) {
        int ix = i ^ j;
        if (ix > i) {
          u64 x = a[i], y = a[ix];
          bool up = ((i & k) == 0);
          if ((x > y) == up) { a[i] = y; a[ix] = x; }
        }
      }
    }
  __syncthreads();
}

// =====================  MLP layers (f16 MFMA; waves 0-3 only)  =====================
template <int Kdim, int Ndim, int SIN, int SOUT>
DI void mfma_layer(const _Float16* __restrict__ Xin, _Float16* __restrict__ Xout,
                   const _Float16* __restrict__ Wsw, const float* __restrict__ bias,
                   int wave, int lane) {
  constexpr int NKS = Kdim / 32;
  constexpr int NTW = Ndim / 64;
  constexpr int CH = (NTW < 4) ? NTW : 4;
  const int quad = lane >> 4, l16 = lane & 15;
  for (int c0 = 0; c0 < NTW; c0 += CH) {
    f32x4 acc[CH][4];
#pragma unroll
    for (int nt = 0; nt < CH; ++nt) {
      float bv = bias[wave * (Ndim / 4) + (c0 + nt) * 16 + l16];
#pragma unroll
      for (int m = 0; m < 4; ++m) acc[nt][m] = {bv, bv, bv, bv};
    }
#pragma unroll
    for (int ks = 0; ks < NKS; ++ks) {
      f16x8 af[4];
#pragma unroll
      for (int m = 0; m < 4; ++m)
        af[m] = *(const f16x8*)(Xin + (m * 16 + l16) * SIN + ks * 32 + quad * 8);
#pragma unroll
      for (int nt = 0; nt < CH; ++nt) {
        int ntg = wave * NTW + c0 + nt;
        f16x8 bf = *(const f16x8*)(Wsw + ((size_t)(ntg * NKS + ks) * 64 + lane) * 8);
#pragma unroll
        for (int m = 0; m < 4; ++m)
          acc[nt][m] = __builtin_amdgcn_mfma_f32_16x16x32_f16(af[m], bf, acc[nt][m], 0, 0, 0);
      }
    }
#pragma unroll
    for (int nt = 0; nt < CH; ++nt) {
      int col = wave * (Ndim / 4) + (c0 + nt) * 16 + l16;
#pragma unroll
      for (int m = 0; m < 4; ++m)
#pragma unroll
        for (int r = 0; r < 4; ++r) {
          int row = m * 16 + quad * 4 + r;
          Xout[row * SOUT + col] = (_Float16)fmaxf(acc[nt][m][r], 0.f);
        }
    }
  }
}

DI void mfma_layer4(const _Float16* __restrict__ Xin, const _Float16* __restrict__ Wsw,
                    const float* __restrict__ bias, float* __restrict__ maxv,
                    int wave, int lane) {
  constexpr int SIN = 264, NKS = 8, NTW = 8, CH = 4;
  const int quad = lane >> 4, l16 = lane & 15;
  for (int c0 = 0; c0 < NTW; c0 += CH) {
    f32x4 acc[CH][4];
#pragma unroll
    for (int nt = 0; nt < CH; ++nt) {
      float bv = bias[wave * 128 + (c0 + nt) * 16 + l16];
#pragma unroll
      for (int m = 0; m < 4; ++m) acc[nt][m] = {bv, bv, bv, bv};
    }
#pragma unroll
    for (int ks = 0; ks < NKS; ++ks) {
      f16x8 af[4];
#pragma unroll
      for (int m = 0; m < 4; ++m)
        af[m] = *(const f16x8*)(Xin + (m * 16 + l16) * SIN + ks * 32 + quad * 8);
#pragma unroll
      for (int nt = 0; nt < CH; ++nt) {
        int ntg = wave * NTW + c0 + nt;
        f16x8 bf = *(const f16x8*)(Wsw + ((size_t)(ntg * NKS + ks) * 64 + lane) * 8);
#pragma unroll
        for (int m = 0; m < 4; ++m)
          acc[nt][m] = __builtin_amdgcn_mfma_f32_16x16x32_f16(af[m], bf, acc[nt][m], 0, 0, 0);
      }
    }
#pragma unroll
    for (int nt = 0; nt < CH; ++nt) {
      float mx = 0.f;  // relu folded into max
#pragma unroll
      for (int m = 0; m < 4; ++m)
#pragma unroll
        for (int r = 0; r < 4; ++r) mx = fmaxf(mx, acc[nt][m][r]);
      mx = fmaxf(mx, __shfl_xor(mx, 16, 64));
      mx = fmaxf(mx, __shfl_xor(mx, 32, 64));
      if (quad == 0) maxv[wave * 128 + (c0 + nt) * 16 + l16] = mx;
    }
  }
}

// =====================  fused kernel  =====================
__global__ __launch_bounds__(TPB, 2) void k_fused(
    const float* __restrict__ xyz, const float* __restrict__ color,
    float* __restrict__ outC, float* __restrict__ outE,
    u64* __restrict__ cline, uint32_t* __restrict__ ccnt,
    uint32_t* __restrict__ cstart, uint32_t* __restrict__ cur,
    float4* __restrict__ sorted, float* __restrict__ dd_g,
    uint32_t* __restrict__ gs,
    const _Float16* __restrict__ sw1, const _Float16* __restrict__ sw2,
    const _Float16* __restrict__ sw3, const _Float16* __restrict__ sw4,
    const float* __restrict__ wpt,
    const float* __restrict__ b1, const float* __restrict__ b2,
    const float* __restrict__ b3, const float* __restrict__ b4,
    const float* __restrict__ bp) {
  __shared__ __align__(16) char smem[65536];
  const int bi = blockIdx.x;
  if (bi < kB) {  // FPS block for batch bi (own CU: 256 blocks on 256 CUs)
    fps_block(xyz, outC, cline, gs, sorted, cstart, dd_g, bi, smem);
    return;
  }

  // ---------------- worker block ----------------
  const int wj = bi - kB;  // 0..251
  const int tid = threadIdx.x;
  const int wave = tid >> 6, lane = tid & 63;
  __shared__ int nC;
  __shared__ float4 spc;
  __shared__ uint32_t s_part[TPB];
  u64* cand = (u64*)smem;

  // ---- grid build (single 16^3 grid for KNN + FPS) ----
  for (int i = wj * TPB + tid; i < kB * kN; i += NWORK * TPB) {
    int b = i >> 16, p = i & (kN - 1);
    const float* q = xyz + ((size_t)b * kN + p) * 3;
    int cid = (cellof(q[2]) * GRD + cellof(q[1])) * GRD + cellof(q[0]);
    atomicAdd(&ccnt[b * NCELL + cid], 1u);
  }
  gbar(gs + 0, NWORK);
  if (wj < kB) {
    int b = wj;
    const uint32_t* cc = ccnt + (size_t)b * NCELL;
    uint32_t* cs = cstart + (size_t)b * (NCELL + 1);
    uint32_t* cu = cur + (size_t)b * NCELL;
    const int chunk = NCELL / TPB;   // 8
    int c0 = tid * chunk;
    uint32_t s = 0;
    for (int i = 0; i < chunk; ++i) s += cc[c0 + i];
    s_part[tid] = s;
    __syncthreads();
    for (int off = 1; off < TPB; off <<= 1) {
      uint32_t add = (tid >= off) ? s_part[tid - off] : 0u;
      __syncthreads();
      s_part[tid] += add;
      __syncthreads();
    }
    uint32_t run = s_part[tid] - s;
    for (int i = 0; i < chunk; ++i) {
      int c = c0 + i;
      cs[c] = run; cu[c] = run; run += cc[c];
    }
    if (tid == TPB - 1) cs[NCELL] = run;
  }
  gbar(gs + 1, NWORK);
  for (int i = wj * TPB + tid; i < kB * kN; i += NWORK * TPB) {
    int b = i >> 16, p = i & (kN - 1);
    const float* q = xyz + ((size_t)b * kN + p) * 3;
    float x = q[0], y = q[1], z = q[2];
    int cid = (cellof(z) * GRD + cellof(y)) * GRD + cellof(x);
    uint32_t pos = atomicAdd(&cur[b * NCELL + cid], 1u);
    sorted[(size_t)b * kN + pos] = make_float4(x, y, z, __uint_as_float((unsigned)p));
  }
  gbar(gs + 2, NWORK);   // FPS blocks wait on this counter

  // ---- consume groups in production order: job j = it*4 + b ----
  for (int j = wj; j < kB * kG; j += NWORK) {
    const int it = j >> 2, b = j & 3;
    if (tid < 64) {
      const u64* e = cline + ((size_t)b * kG + it) * 16;
      u64 v = 0; long bail = 0;
      for (;;) {
        if (lane < 3)
          v = __hip_atomic_load(e + lane, __ATOMIC_RELAXED, __HIP_MEMORY_SCOPE_AGENT);
        bool ok = (lane >= 3) || ((unsigned)v == (unsigned)(it + 1));
        if (__all(ok)) break;
        __builtin_amdgcn_s_sleep(8);
        if (++bail > 100000000L) break;
      }
      u64 v0 = __shfl(v, 0), v1 = __shfl(v, 1), v2 = __shfl(v, 2);
      if (tid == 0)
        spc = make_float4(__uint_as_float((unsigned)(v0 >> 32)),
                          __uint_as_float((unsigned)(v1 >> 32)),
                          __uint_as_float((unsigned)(v2 >> 32)), 0.f);
    }
    __syncthreads();
    const float cx = spc.x, cy = spc.y, cz = spc.z;

    // ---- KNN (expanding box + exact re-rank + bitonic) ----
    const float nc = __fadd_rn(__fadd_rn(__fmul_rn(cx, cx), __fmul_rn(cy, cy)), __fmul_rn(cz, cz));
    const float4* SPb = sorted + (size_t)b * kN;
    const uint32_t* CS = cstart + (size_t)b * (NCELL + 1);
    const int ccx = cellof(cx), ccy = cellof(cy), ccz = cellof(cz);
    if (tid == 0) nC = 0;
    __syncthreads();
    int plox = 1, phix = 0, ploy = 1, phiy = 0, ploz = 1, phiz = 0;
    for (int r = 1; r <= GRD; ++r) {
      int lox = max(0, ccx - r), hix = min(GRD - 1, ccx + r);
      int loy = max(0, ccy - r), hiy = min(GRD - 1, ccy + r);
      int loz = max(0, ccz - r), hiz = min(GRD - 1, ccz + r);
      for (int z = loz; z <= hiz; ++z)
        for (int y = loy; y <= hiy; ++y) {
          bool rowPrev = (r > 1) && (z >= ploz && z <= phiz && y >= ploy && y <= phiy);
          for (int s = 0; s < 2; ++s) {
            int xa, xb;
            if (!rowPrev) { if (s) break; xa = lox; xb = hix; }
            else if (s == 0) { xa = lox; xb = plox - 1; }
            else { xa = phix + 1; xb = hix; }
            if (xa > xb) continue;
            int c0 = (z * GRD + y) * GRD + xa;
            int i0 = CS[c0];
            int i1 = CS[(z * GRD + y) * GRD + xb + 1];
            for (int i = i0 + tid; i < i1; i += TPB) {
              float4 pt = SPb[i];
              float npn = __fadd_rn(__fadd_rn(__fmul_rn(pt.x, pt.x), __fmul_rn(pt.y, pt.y)),
                                    __fmul_rn(pt.z, pt.z));
              float dot = __fadd_rn(__fadd_rn(__fmul_rn(cx, pt.x), __fmul_rn(cy, pt.y)),
                                    __fmul_rn(cz, pt.z));
              float sq = __fsub_rn(__fadd_rn(nc, npn), __fmul_rn(2.0f, dot));
              unsigned key = orderable(sq);
              int pos = atomicAdd(&nC, 1);
              if (pos < 8192)
                cand[pos] = ((u64)key << 32) | (unsigned)__float_as_uint(pt.w);
            }
          }
        }
      __syncthreads();
      int n = min(nC, 8192);
      float rc = 1e30f;
      if (lox > 0) rc = fminf(rc, cx - (float)lox * CW);
      if (hix < GRD - 1) rc = fminf(rc, (float)(hix + 1) * CW - cx);
      if (loy > 0) rc = fminf(rc, cy - (float)loy * CW);
      if (hiy < GRD - 1) rc = fminf(rc, (float)(hiy + 1) * CW - cy);
      if (loz > 0) rc = fminf(rc, cz - (float)loz * CW);
      if (hiz < GRD - 1) rc = fminf(rc, (float)(hiz + 1) * CW - cz);
      float r2 = (rc >= 1e29f) ? 3.0e38f : rc * rc * (1.0f - 1e-5f);
      unsigned keyR = orderable(r2);
      bool done = false;
      if (n >= kM) {
        int np2 = 1;
        while (np2 < n) np2 <<= 1;
        for (int i = n + tid; i < np2; i += TPB) cand[i] = ~0ull;
        bitonic(cand, np2, tid);
        unsigned k63 = (unsigned)(cand[kM - 1] >> 32);
        done = (k63 <= keyR);
        if (tid == 0) nC = n;
      }
      __syncthreads();
      if (done) break;
      plox = lox; phix = hix; ploy = loy; phiy = hiy; ploz = loz; phiz = hiz;
    }

    // ---- MLP (waves 0-3 compute; waves 4-7 only hit barriers) ----
    uint32_t pidx = 0;
    if (tid < kM) pidx = (uint32_t)(cand[tid] & 0xFFFFFFFFu);
    __syncthreads();
    _Float16* bufA = (_Float16*)smem;
    _Float16* bufB = (_Float16*)(smem + 17408);
    float* maxv = (float*)smem;
    float* psum = (float*)(smem + 2048);
    if (tid < kM) {
      const float* xp = xyz + ((size_t)b * kN + pidx) * 3;
      const float* cp = color + ((size_t)b * kN + pidx) * 3;
      f16x8 v = {};
      v[0] = (_Float16)__fsub_rn(xp[0], cx);
      v[1] = (_Float16)__fsub_rn(xp[1], cy);
      v[2] = (_Float16)__fsub_rn(xp[2], cz);
      v[3] = (_Float16)cp[0];
      v[4] = (_Float16)cp[1];
      v[5] = (_Float16)cp[2];
      f16x8 zf = {};
      *(f16x8*)(bufA + tid * 40 + 0) = v;
      *(f16x8*)(bufA + tid * 40 + 8) = zf;
      *(f16x8*)(bufA + tid * 40 + 16) = zf;
      *(f16x8*)(bufA + tid * 40 + 24) = zf;
    }
    __syncthreads();
    if (tid < 256) mfma_layer<32, 64, 40, 72>(bufA, bufB, sw1, b1, wave, lane);
    __syncthreads();
    if (tid < 256) mfma_layer<64, 128, 72, 136>(bufB, bufA, sw2, b2, wave, lane);
    __syncthreads();
    if (tid < 256) mfma_layer<128, 256, 136, 264>(bufA, bufB, sw3, b3, wave, lane);
    __syncthreads();
    if (tid < 256) mfma_layer4(bufB, sw4, b4, maxv, wave, lane);
    __syncthreads();
    if (tid < 240) {
      int jj = tid >> 2, q = tid & 3;
      const float* w = wpt + (size_t)jj * 512 + q * 128;
      float s = 0.f;
#pragma unroll 4
      for (int k = 0; k < 128; ++k) s = fmaf(maxv[q * 128 + k], w[k], s);
      psum[tid] = s;
    }
    __syncthreads();
    if (tid < kE) {
      float e = __fadd_rn(__fadd_rn(psum[tid * 4 + 0], psum[tid * 4 + 1]),
                          __fadd_rn(psum[tid * 4 + 2], psum[tid * 4 + 3])) + bp[tid];
      outE[((size_t)b * kG + it) * kE + tid] = e;
    }
    __syncthreads();  // smem reuse fence before next job
  }
}

// =====================  launch  =====================
extern "C" void kernel_launch(void* const* d_in, const int* in_sizes, int n_in,
                              void* d_out, int out_size, void* d_ws, size_t ws_size,
                              hipStream_t stream) {
  (void)in_sizes; (void)n_in; (void)out_size; (void)ws_size;
  const float* xyz = (const float*)d_in[0];
  const float* color = (const float*)d_in[1];
  const float* W1 = (const float*)d_in[2];
  const float* b1 = (const float*)d_in[3];
  const float* W2 = (const float*)d_in[4];
  const float* b2 = (const float*)d_in[5];
  const float* W3 = (const float*)d_in[6];
  const float* b3 = (const float*)d_in[7];
  const float* W4 = (const float*)d_in[8];
  const float* b4 = (const float*)d_in[9];
  const float* Wp = (const float*)d_in[10];
  const float* bp = (const float*)d_in[11];

  char* ws = (char*)d_ws;
  auto cline = (u64*)(ws + OFF_CLINE);
  auto ccnt = (uint32_t*)(ws + OFF_CCNT);
  auto gs = (uint32_t*)(ws + OFF_GS);
  auto cstart = (uint32_t*)(ws + OFF_CSTART);
  auto cur = (uint32_t*)(ws + OFF_CUR);
  auto dd = (float*)(ws + OFF_DD);
  auto sw1 = (_Float16*)(ws + OFF_SW1);
  auto sw2 = (_Float16*)(ws + OFF_SW2);
  auto sw3 = (_Float16*)(ws + OFF_SW3);
  auto sw4 = (_Float16*)(ws + OFF_SW4);
  auto wpt = (float*)(ws + OFF_WPT);
  auto sorted = (float4*)(ws + OFF_SORT);

  float* outE = (float*)d_out;
  float* outC = outE + (size_t)kB * kG * kE;

  k_zero<<<256, 256, 0, stream>>>((uint32_t*)ws, (int)(ZERO_BYTES / 4));
  k_prep<<<256, 256, 0, stream>>>(W1, W2, W3, W4, Wp, sw1, sw2, sw3, sw4, wpt);
  k_fused<<<NBLK, TPB, 0, stream>>>(xyz, color, outC, outE, cline, ccnt, cstart,
                                    cur, sorted, dd, gs, sw1, sw2, sw3, sw4, wpt,
                                    b1, b2, b3, b4, bp);
}